// Round 19
// baseline (389.616 us; speedup 1.0000x reference)
//
#include <hip/hip_runtime.h>
#include <hip/hip_bf16.h>
#include <stdint.h>

#define NN 65536
#define DD 256

typedef uint32_t u32;
typedef __attribute__((ext_vector_type(4))) float f32x4;
typedef __attribute__((ext_vector_type(4))) u32 u32x4;
typedef __attribute__((ext_vector_type(2))) u32 u32x2;
typedef __attribute__((ext_vector_type(8))) short s16x8;

__device__ inline unsigned short f2bf(float f) {
    union { float f; u32 u; } v; v.f = f;
    u32 u = v.u;
    return (unsigned short)((u + 0x7fffu + ((u >> 16) & 1u)) >> 16);
}

__device__ inline float bf2f(unsigned short h) {
    union { u32 u; float f; } v; v.u = (u32)h << 16;
    return v.f;
}

__device__ inline void gl2lds16(const void* g, void* s) {
    __builtin_amdgcn_global_load_lds(
        (const __attribute__((address_space(1))) void*)g,
        (__attribute__((address_space(3))) void*)s, 16, 0, 0);
}

// ---- Small prep: blocks [0,1024) = Wimg (128-col tiles, R2-verified),
// [1024,1028) = bsum. Block-uniform branch.
__global__ void prep_small(const float* __restrict__ W, const float* __restrict__ b,
                           unsigned short* __restrict__ Wimg, float* __restrict__ bsum) {
    int bid = blockIdx.x;
    if (bid < 1024) {
        int t = bid * 256 + threadIdx.x;
        int E = t * 4;
        int tile = E >> 13;
        int pin = E & 8191;
        int col = pin >> 6;
        int r2e = pin & 63;
        int ct = tile >> 4;
        int j = (tile >> 2) & 3;
        int kk = tile & 3;
        int kl = r2e ^ ((col & 7) << 3);
        int c = ct * 128 + col;
        int i = c >> 8, e = c & 255;
        int f = kk * 64 + kl;
        u32 p0, p1;
        if (i == j) {
            p0 = 0u; p1 = 0u;    // j==i K-tiles never read
        } else {
            f32x4 w = *(const f32x4*)(W + ((size_t)((i * 4 + j) * 256 + e) << 8) + f);
            p0 = (u32)f2bf(w[0]) | ((u32)f2bf(w[1]) << 16);
            p1 = (u32)f2bf(w[2]) | ((u32)f2bf(w[3]) << 16);
        }
        u32x2 pr = {p0, p1};
        *(u32x2*)(Wimg + E) = pr;
    } else {
        int c = (bid - 1024) * 256 + threadIdx.x;
        if (c < 1024) {
            int i = c >> 8, e = c & 255;
            float s = 0.0f;
            #pragma unroll
            for (int j = 0; j < 4; ++j)
                if (j != i) s += b[((i * 4 + j) << 8) + e];
            bsum[c] = s;
        }
    }
}

// ---- Fused producer-consumer GEMM: 256x128 tile, BK=64, K=768 (j != i).
// Waves 0-3 = consumers (gemm14 MFMA structure, 128x64 out each, acc[8][4]).
// Waves 4-7 = producers: stage A directly from f32 x (convert in-wave, R2-fb
// verified swizzled ds_write pattern) + B via 4x global_load_lds per thread
// (R18 bug: was 1x -> 3/4 of B stale). One lgkm+vmcnt+barrier per K-tile.
// Producer stalls hide under consumer MFMA (m114). prep_x/Ximg eliminated.
__global__ __launch_bounds__(512, 2) void fusion_gemm17(
    const float* __restrict__ x, const unsigned short* __restrict__ Wimg,
    const float* __restrict__ bsum, float* __restrict__ out) {
    __shared__ __attribute__((aligned(16))) char lds[2][49152];  // [buf]{A 32K | B 16K}

    const int tid = threadIdx.x;
    const int bid = blockIdx.x;
    const int xcd = bid & 7;
    const int slot = bid >> 3;
    const int ct = slot & 7;            // col tile (128 cols); i = ct>>1
    const int rhi = slot >> 3;          // 0..31
    const int rtile = rhi * 8 + xcd;    // 0..255 ; 8 ct-blocks share x panel per XCD
    const int n0 = rtile * 256;
    const int i = ct >> 1;

    const int lane = tid & 63;
    const int wid = tid >> 6;
    const bool consumer = (wid < 4);
    const int wm = wid & 1;             // consumer: row half (128 rows)
    const int wn = (wid >> 1) & 1;      // consumer: col half (64 cols)
    const int p = tid - 256;            // producer thread id 0..255 (row)
    const int pw = wid - 4;             // producer wave 0..3

    f32x4 acc[8][4];
    #pragma unroll
    for (int a = 0; a < 8; ++a)
        #pragma unroll
        for (int b2 = 0; b2 < 4; ++b2)
            acc[a][b2] = (f32x4){0.f, 0.f, 0.f, 0.f};

    const char* WimgB = (const char*)Wimg;
    s16x8 fA0[2][4], fA1[2][4];   // consumer A frags
    s16x8 fB0[2][2], fB1[2][2];   // consumer B frags

    // ---- producer: issue x f32 loads for one row of the A tile ----
#define P_LOAD(j_, kk_)                                                               \
    {                                                                                 \
        const float* as_ = x + (size_t)(j_) * ((size_t)NN * DD)                       \
                           + (size_t)(n0 + p) * DD + (kk_) * 64;                      \
        _Pragma("unroll")                                                             \
        for (int q = 0; q < 16; ++q) av[q] = *(const f32x4*)(as_ + q * 4);            \
    }

    // ---- producer: stage full 16KB B tile (4 waves x 4KB; 4 DMAs/thread) ----
#define P_BDMA(j_, kk_, D_)                                                           \
    {                                                                                 \
        const char* bs_ = WimgB + (((size_t)((ct * 4 + (j_)) * 4 + (kk_))) << 14)     \
                          + pw * 4096 + lane * 16;                                    \
        _Pragma("unroll")                                                             \
        for (int q = 0; q < 4; ++q)                                                   \
            gl2lds16(bs_ + q * 1024, (D_) + 32768 + pw * 4096 + q * 1024);            \
    }

    // convert av -> bf16 row p, swizzled write into A region of D_
#define P_WRITE_A(D_)                                                                 \
    {                                                                                 \
        _Pragma("unroll")                                                             \
        for (int q = 0; q < 8; ++q) {                                                 \
            f32x4 v0 = av[2 * q], v1 = av[2 * q + 1];                                 \
            u32x4 pk;                                                                 \
            pk[0] = (u32)f2bf(v0[0]) | ((u32)f2bf(v0[1]) << 16);                      \
            pk[1] = (u32)f2bf(v0[2]) | ((u32)f2bf(v0[3]) << 16);                      \
            pk[2] = (u32)f2bf(v1[0]) | ((u32)f2bf(v1[1]) << 16);                      \
            pk[3] = (u32)f2bf(v1[2]) | ((u32)f2bf(v1[3]) << 16);                      \
            u32 o_ = (u32)(p * 128 + q * 16);                                         \
            o_ ^= (u32)((p & 7) << 4);                                                \
            *(u32x4*)((D_) + o_) = pk;                                                \
        }                                                                             \
    }

#define RD_A(BUF_, mh_, SET_)                                                         \
    _Pragma("unroll")                                                                 \
    for (int kh = 0; kh < 2; ++kh) {                                                  \
        _Pragma("unroll")                                                             \
        for (int fm = 0; fm < 4; ++fm) {                                              \
            int r_ = wm * 128 + ((mh_) * 4 + fm) * 16 + (lane & 15);                  \
            u32 o_ = (u32)(r_ * 128 + kh * 64 + (lane >> 4) * 16);                    \
            o_ ^= (u32)((r_ & 7) << 4);                                               \
            SET_[kh][fm] = *(const s16x8*)((BUF_) + o_);                              \
        }                                                                             \
    }

#define RD_B(BUF_, nh_, SET_)                                                         \
    _Pragma("unroll")                                                                 \
    for (int kh = 0; kh < 2; ++kh) {                                                  \
        _Pragma("unroll")                                                             \
        for (int fn = 0; fn < 2; ++fn) {                                              \
            int c_ = wn * 64 + ((nh_) * 2 + fn) * 16 + (lane & 15);                   \
            u32 o_ = (u32)(c_ * 128 + kh * 64 + (lane >> 4) * 16);                    \
            o_ ^= (u32)((c_ & 7) << 4);                                               \
            SET_[kh][fn] = *(const s16x8*)((BUF_) + 32768 + o_);                      \
        }                                                                             \
    }

#define MM(AS_, BS_, mh_, nh_)                                                        \
    _Pragma("unroll")                                                                 \
    for (int kh = 0; kh < 2; ++kh) {                                                  \
        _Pragma("unroll")                                                             \
        for (int fm = 0; fm < 4; ++fm) {                                              \
            _Pragma("unroll")                                                         \
            for (int fn = 0; fn < 2; ++fn) {                                          \
                acc[(mh_) * 4 + fm][(nh_) * 2 + fn] =                                 \
                    __builtin_amdgcn_mfma_f32_16x16x32_bf16(                          \
                        AS_[kh][fm], BS_[kh][fn],                                     \
                        acc[(mh_) * 4 + fm][(nh_) * 2 + fn], 0, 0, 0);                \
            }                                                                         \
        }                                                                             \
    }

    // ---- prologue: producers stage tile 0 -> buf 0 ----
    if (!consumer) {
        f32x4 av[16];
        int jj = 0, j0 = jj + (jj >= i);
        P_LOAD(j0, 0);
        P_BDMA(j0, 0, (char*)lds[0]);
        P_WRITE_A((char*)lds[0]);
    }
    asm volatile("s_waitcnt lgkmcnt(0)" ::: "memory");
    asm volatile("s_waitcnt vmcnt(0)" ::: "memory");
    __builtin_amdgcn_s_barrier();
    __builtin_amdgcn_sched_barrier(0);

    #pragma unroll 1
    for (int t = 0; t < 12; ++t) {
        const char* Bf = lds[t & 1];
        char* Of = lds[(t + 1) & 1];

        if (consumer) {
            RD_A(Bf, 0, fA0);
            RD_B(Bf, 0, fB0);
            __builtin_amdgcn_s_setprio(1);
            MM(fA0, fB0, 0, 0);
            RD_B(Bf, 1, fB1);
            MM(fA0, fB1, 0, 1);
            RD_A(Bf, 1, fA1);
            MM(fA1, fB1, 1, 1);
            MM(fA1, fB0, 1, 0);
            __builtin_amdgcn_s_setprio(0);
        } else if (t < 11) {
            f32x4 av[16];
            int jj = (t + 1) >> 2;
            int jn = jj + (jj >= i);
            int kkn = (t + 1) & 3;
            P_LOAD(jn, kkn);
            P_BDMA(jn, kkn, Of);
            P_WRITE_A(Of);
        }

        asm volatile("s_waitcnt lgkmcnt(0)" ::: "memory");
        asm volatile("s_waitcnt vmcnt(0)" ::: "memory");
        __builtin_amdgcn_s_barrier();
        __builtin_amdgcn_sched_barrier(0);
    }

    // ---- residual: producers stage the 2 needed x[i] quarters (bf16, image
    // layout) into the A regions of both buffers; consumers then read via the
    // R15-verified swizzled ds_read_u16 path. Last tile's reads retired above.
    if (!consumer) {
        #pragma unroll
        for (int h = 0; h < 2; ++h) {
            f32x4 av[16];
            int kkr = (ct & 1) * 2 + h;
            P_LOAD(i, kkr);
            P_WRITE_A((char*)lds[h]);
        }
    }
    asm volatile("s_waitcnt lgkmcnt(0)" ::: "memory");
    asm volatile("s_waitcnt vmcnt(0)" ::: "memory");
    __builtin_amdgcn_s_barrier();
    __builtin_amdgcn_sched_barrier(0);

#undef P_LOAD
#undef P_BDMA
#undef P_WRITE_A
#undef RD_A
#undef RD_B
#undef MM

    // ---- epilogue (consumers only): out = acc + bf16(x[i]) + bsum ----
    if (consumer) {
        const int r0 = (lane >> 4) * 4;
        const int cl = lane & 15;
        const char* Rb = (const char*)lds[wn];     // quarter h == wn
        #pragma unroll
        for (int mf = 0; mf < 8; ++mf) {
            #pragma unroll
            for (int nf = 0; nf < 4; ++nf) {
                int col_l = wn * 64 + nf * 16 + cl;
                int e = (ct & 1) * 128 + col_l;
                float bs = bsum[i * 256 + e];
                #pragma unroll
                for (int r = 0; r < 4; ++r) {
                    int row = wm * 128 + mf * 16 + r0 + r;     // [0,256)
                    int r2e = (nf * 16 + cl) ^ ((row & 7) << 3);
                    float res = bf2f(*(const unsigned short*)(Rb + row * 128 + r2e * 2));
                    int n = n0 + row;
                    size_t oidx = ((size_t)i * NN + n) * DD + e;
                    out[oidx] = acc[mf][nf][r] + res + bs;
                }
            }
        }
    }
}

// ---- Fallback (R2-verified kernel) for tiny ws_size ----
__global__ __launch_bounds__(256, 2) void fusion_gemm_fb(
    const float* __restrict__ x, const unsigned short* __restrict__ Wimg,
    const float* __restrict__ bsum, float* __restrict__ out) {
    __shared__ __attribute__((aligned(16))) unsigned short Alds[128 * 64];
    __shared__ __attribute__((aligned(16))) unsigned short Blds[2][128 * 64];

    const int tid = threadIdx.x;
    const int bid = blockIdx.x;
    const int xcd = bid & 7;
    const int slot = bid >> 3;
    const int ct = slot & 7;
    const int rhi = slot >> 3;
    const int rtile = rhi * 8 + xcd;
    const int n0 = rtile * 128;
    const int col0 = ct * 128;
    const int i = ct >> 1;

    const int lane = tid & 63;
    const int wid = tid >> 6;
    const int wm = wid >> 1;
    const int wn = wid & 1;

    f32x4 acc[4][4];
    #pragma unroll
    for (int a = 0; a < 4; ++a)
        #pragma unroll
        for (int b2 = 0; b2 < 4; ++b2)
            acc[a][b2] = (f32x4){0.f, 0.f, 0.f, 0.f};

    const int sr = tid >> 1;
    const int sh = tid & 1;
    char* Ab = (char*)Alds;
    const char* WimgB = (const char*)Wimg;

    f32x4 av[8];
    {
        int j0 = (i == 0) ? 1 : 0;
        const float* asrc = x + (size_t)j0 * ((size_t)NN * DD) + (size_t)(n0 + sr) * DD + sh * 32;
        #pragma unroll
        for (int q = 0; q < 8; ++q) av[q] = *(const f32x4*)(asrc + q * 4);
        const char* base = WimgB + (((size_t)(ct * 4 + j0) * 4 + 0) << 14) + wid * 1024 + lane * 16;
        char* lb = (char*)Blds[0] + wid * 1024;
        #pragma unroll
        for (int q = 0; q < 4; ++q) gl2lds16(base + q * 4096, lb + q * 4096);
    }

    for (int t = 0; t < 12; ++t) {
        __syncthreads();
        #pragma unroll
        for (int q = 0; q < 4; ++q) {
            f32x4 v0 = av[2 * q], v1 = av[2 * q + 1];
            u32x4 pk;
            pk[0] = (u32)f2bf(v0[0]) | ((u32)f2bf(v0[1]) << 16);
            pk[1] = (u32)f2bf(v0[2]) | ((u32)f2bf(v0[3]) << 16);
            pk[2] = (u32)f2bf(v1[0]) | ((u32)f2bf(v1[1]) << 16);
            pk[3] = (u32)f2bf(v1[2]) | ((u32)f2bf(v1[3]) << 16);
            u32 o = (u32)(sr * 128 + sh * 64 + q * 16);
            o ^= (u32)((sr & 7) << 4);
            *(u32x4*)(Ab + o) = pk;
        }
        __syncthreads();

        if (t < 11) {
            int tn = t + 1;
            int jjn = tn >> 2;
            int jn = jjn + (jjn >= i);
            int kkn = tn & 3;
            const char* base = WimgB + (((size_t)(ct * 4 + jn) * 4 + kkn) << 14) + wid * 1024 + lane * 16;
            char* lb = (char*)Blds[tn & 1] + wid * 1024;
            #pragma unroll
            for (int q = 0; q < 4; ++q) gl2lds16(base + q * 4096, lb + q * 4096);
            const float* asrc = x + (size_t)jn * ((size_t)NN * DD) + (size_t)(n0 + sr) * DD + kkn * 64 + sh * 32;
            #pragma unroll
            for (int q = 0; q < 8; ++q) av[q] = *(const f32x4*)(asrc + q * 4);
        }

        const char* Bb = (const char*)Blds[t & 1];
        #pragma unroll
        for (int kh = 0; kh < 2; ++kh) {
            s16x8 af[4], bfr[4];
            #pragma unroll
            for (int fm = 0; fm < 4; ++fm) {
                int row = wm * 64 + fm * 16 + (lane & 15);
                u32 o = (u32)(row * 128 + kh * 64 + (lane >> 4) * 16);
                o ^= (u32)((row & 7) << 4);
                af[fm] = *(const s16x8*)(Ab + o);
            }
            #pragma unroll
            for (int fn = 0; fn < 4; ++fn) {
                int col = wn * 64 + fn * 16 + (lane & 15);
                u32 o = (u32)(col * 128 + kh * 64 + (lane >> 4) * 16);
                o ^= (u32)((col & 7) << 4);
                bfr[fn] = *(const s16x8*)(Bb + o);
            }
            #pragma unroll
            for (int fm = 0; fm < 4; ++fm)
                #pragma unroll
                for (int fn = 0; fn < 4; ++fn)
                    acc[fm][fn] = __builtin_amdgcn_mfma_f32_16x16x32_bf16(
                        af[fm], bfr[fn], acc[fm][fn], 0, 0, 0);
        }
    }

    const int r0 = (lane >> 4) * 4;
    const int cl = lane & 15;
    #pragma unroll
    for (int fm = 0; fm < 4; ++fm) {
        #pragma unroll
        for (int fn = 0; fn < 4; ++fn) {
            int col_l = wn * 64 + fn * 16 + cl;
            int cglob = col0 + col_l;
            float bs = bsum[cglob];
            int e = cglob & 255;
            #pragma unroll
            for (int r = 0; r < 4; ++r) {
                int row_l = wm * 64 + fm * 16 + r0 + r;
                int n = n0 + row_l;
                size_t oidx = ((size_t)i * NN + n) * DD + e;
                out[oidx] = acc[fm][fn][r] + x[oidx] + bs;
            }
        }
    }
}

extern "C" void kernel_launch(void* const* d_in, const int* in_sizes, int n_in,
                              void* d_out, int out_size, void* d_ws, size_t ws_size,
                              hipStream_t stream) {
    const float* x = (const float*)d_in[0];
    const float* W = (const float*)d_in[1];
    const float* b = (const float*)d_in[2];
    float* out = (float*)d_out;

    unsigned short* Wimg = (unsigned short*)d_ws;                      // 2 MB
    float* bsum = (float*)((char*)d_ws + ((size_t)2 << 20));           // 4 KB
    const size_t need = ((size_t)2 << 20) + 4096;

    hipLaunchKernelGGL(prep_small, dim3(1028), dim3(256), 0, stream, W, b, Wimg, bsum);

    if (ws_size >= need) {
        hipLaunchKernelGGL(fusion_gemm17, dim3(2048), dim3(512), 0, stream, x, Wimg, bsum, out);
    } else {
        hipLaunchKernelGGL(fusion_gemm_fb, dim3(4096), dim3(256), 0, stream, x, Wimg, bsum, out);
    }
}

// Round 20
// 213.847 us; speedup vs baseline: 1.8219x; 1.8219x over previous
//
#include <hip/hip_runtime.h>
#include <hip/hip_bf16.h>
#include <stdint.h>

#define NN 65536
#define DD 256

typedef uint32_t u32;
typedef __attribute__((ext_vector_type(4))) float f32x4;
typedef __attribute__((ext_vector_type(4))) u32 u32x4;
typedef __attribute__((ext_vector_type(2))) u32 u32x2;
typedef __attribute__((ext_vector_type(8))) short s16x8;

__device__ inline unsigned short f2bf(float f) {
    union { float f; u32 u; } v; v.f = f;
    u32 u = v.u;
    return (unsigned short)((u + 0x7fffu + ((u >> 16) & 1u)) >> 16);
}

__device__ inline float bf2f(unsigned short h) {
    union { u32 u; float f; } v; v.u = (u32)h << 16;
    return v.f;
}

__device__ inline void gl2lds16(const void* g, void* s) {
    __builtin_amdgcn_global_load_lds(
        (const __attribute__((address_space(1))) void*)g,
        (__attribute__((address_space(3))) void*)s, 16, 0, 0);
}

// ---- Merged prep (R17-verified): blocks [0,65536) = Ximg, [65536,66560) =
// Wimg(256-col), [66560,66564) = bsum. All independent; branch block-uniform.
__global__ void prep_all(const float* __restrict__ x, const float* __restrict__ W,
                         const float* __restrict__ b,
                         unsigned short* __restrict__ Wimg,
                         unsigned short* __restrict__ Ximg,
                         float* __restrict__ bsum) {
    int bid = blockIdx.x;
    if (bid < 65536) {
        // prep_x (R4-verified 256-row tiles): tile (j*256+rt)*4+kk = 32KB image
        // of swizzled A LDS [256 rows][64 K]: pin: row=pin>>6, r2e=pin&63,
        // kl=r2e^((row&7)<<3), value=bf16(x[j][rt*256+row][kk*64+kl]).
        int t = bid * 256 + threadIdx.x;
        long long E = (long long)t * 4;
        int tile = (int)(E >> 14);
        int pin = (int)(E & 16383);
        int row = pin >> 6;
        int r2e = pin & 63;
        int kk = tile & 3;
        int rt = (tile >> 2) & 255;
        int j = tile >> 10;
        int kl = r2e ^ ((row & 7) << 3);
        int n = rt * 256 + row;
        int f = kk * 64 + kl;
        f32x4 v = *(const f32x4*)(x + ((size_t)j * NN + n) * DD + f);
        u32 p0 = (u32)f2bf(v[0]) | ((u32)f2bf(v[1]) << 16);
        u32 p1 = (u32)f2bf(v[2]) | ((u32)f2bf(v[3]) << 16);
        u32x2 pr = {p0, p1};
        *(u32x2*)(Ximg + E) = pr;
    } else if (bid < 65536 + 1024) {
        // prep_w256 (R5-verified): tile (ct,j,kk) = 32KB image of swizzled
        // B LDS [256 cols][64 K]; zero diag (j==i K-tiles never read).
        int t = (bid - 65536) * 256 + threadIdx.x;
        int E = t * 4;
        int tile = E >> 14;
        int pin = E & 16383;
        int col = pin >> 6;
        int r2e = pin & 63;
        int ct = tile >> 4;
        int j = (tile >> 2) & 3;
        int kk = tile & 3;
        int kl = r2e ^ ((col & 7) << 3);
        int i = ct;
        int e = col;
        int f = kk * 64 + kl;
        u32 p0, p1;
        if (i == j) {
            p0 = 0u; p1 = 0u;
        } else {
            f32x4 w = *(const f32x4*)(W + ((size_t)((i * 4 + j) * 256 + e) << 8) + f);
            p0 = (u32)f2bf(w[0]) | ((u32)f2bf(w[1]) << 16);
            p1 = (u32)f2bf(w[2]) | ((u32)f2bf(w[3]) << 16);
        }
        u32x2 pr = {p0, p1};
        *(u32x2*)(Wimg + E) = pr;
    } else {
        // prep_b: bsum[i*256+e] = sum_{j != i} b[i,j,e]
        int c = (bid - 66560) * 256 + threadIdx.x;
        if (c < 1024) {
            int i = c >> 8, e = c & 255;
            float s = 0.0f;
            #pragma unroll
            for (int j = 0; j < 4; ++j)
                if (j != i) s += b[((i * 4 + j) << 8) + e];
            bsum[c] = s;
        }
    }
}

// ---- Pre-swizzled B image, 128-col tiles (fallback path, R2-verified) ----
__global__ void prep_w128(const float* __restrict__ W, unsigned short* __restrict__ Wimg) {
    int t = blockIdx.x * blockDim.x + threadIdx.x;
    int E = t * 4;
    int tile = E >> 13;
    int pin = E & 8191;
    int col = pin >> 6;
    int r2e = pin & 63;
    int ct = tile >> 4;
    int j = (tile >> 2) & 3;
    int kk = tile & 3;
    int kl = r2e ^ ((col & 7) << 3);
    int c = ct * 128 + col;
    int i = c >> 8, e = c & 255;
    int f = kk * 64 + kl;
    u32 p0, p1;
    if (i == j) {
        p0 = 0u; p1 = 0u;
    } else {
        f32x4 w = *(const f32x4*)(W + ((size_t)((i * 4 + j) * 256 + e) << 8) + f);
        p0 = (u32)f2bf(w[0]) | ((u32)f2bf(w[1]) << 16);
        p1 = (u32)f2bf(w[2]) | ((u32)f2bf(w[3]) << 16);
    }
    u32x2 pr = {p0, p1};
    *(u32x2*)(Wimg + E) = pr;
}

// bsum (fallback path)
__global__ void prep_b(const float* __restrict__ b, float* __restrict__ bsum) {
    int c = blockIdx.x * blockDim.x + threadIdx.x;
    if (c >= 1024) return;
    int i = c >> 8, e = c & 255;
    float s = 0.0f;
    #pragma unroll
    for (int j = 0; j < 4; ++j)
        if (j != i) s += b[((i * 4 + j) << 8) + e];
    bsum[c] = s;
}

// ---- Main GEMM (R15/R17-verified best): 256x256 tile, BK=64, 8 waves (2x4),
// K = 768 (j != i only, 12 K-tiles). Residual x[i] staged into the freed LDS
// after the K-loop via coalesced global_load_lds, read as ds_read_u16.
__global__ __launch_bounds__(512, 2) void fusion_gemm14(
    const unsigned short* __restrict__ Wimg, const unsigned short* __restrict__ Ximg,
    const float* __restrict__ bsum, float* __restrict__ out) {
    __shared__ __attribute__((aligned(16))) char lds[2][65536];  // [buf]{A 32K | B 32K}

    const int tid = threadIdx.x;
    const int bid = blockIdx.x;
    const int xcd = bid & 7;
    const int slot = bid >> 3;
    const int ct = slot & 3;            // col tile == output modality i
    const int rhi = slot >> 2;
    const int rtile = rhi * 8 + xcd;
    const int n0 = rtile * 256;
    const int col0 = ct * 256;

    const int lane = tid & 63;
    const int wid = tid >> 6;
    const int wm = wid & 1;             // row half (128 rows)
    const int wn = wid >> 1;            // col quarter (64 cols)

    f32x4 acc[8][4];
    #pragma unroll
    for (int a = 0; a < 8; ++a)
        #pragma unroll
        for (int b2 = 0; b2 < 4; ++b2)
            acc[a][b2] = (f32x4){0.f, 0.f, 0.f, 0.f};

    const char* WimgB = (const char*)Wimg;
    const char* XimgB = (const char*)Ximg;
    const u32 loff = (u32)(wid * 1024);
    const u32 goff = (u32)(wid * 1024 + lane * 16);

    // full-tile fragment registers — static indices only (rule #20)
    s16x8 fA0[2][4], fA1[2][4];   // A rows [wm*128 .. +64) / [+64 .. +128)
    s16x8 fB0[2][2], fB1[2][2];   // B cols [wn*64 .. +32) / [+32 .. +64)

    // K-tile t in [0,12): jj = t>>2, j = jj + (jj >= ct) skips j == i
#define STAGE_TILE(t_, D_)                                                            \
    {                                                                                 \
        int jj_ = (t_) >> 2;                                                          \
        int j_ = jj_ + (jj_ >= ct);                                                   \
        int kk_ = (t_) & 3;                                                           \
        const char* as_ = XimgB + (((size_t)((j_ * 256 + rtile) * 4 + kk_)) << 15) + goff; \
        const char* bs_ = WimgB + (((size_t)((ct * 4 + j_) * 4 + kk_)) << 15) + goff; \
        _Pragma("unroll")                                                             \
        for (int q = 0; q < 4; ++q) {                                                 \
            gl2lds16(as_ + q * 8192, (D_) + q * 8192 + loff);                         \
            gl2lds16(bs_ + q * 8192, (D_) + 32768 + q * 8192 + loff);                 \
        }                                                                             \
    }

#define RD_A(BUF_, mh_, SET_)                                                         \
    _Pragma("unroll")                                                                 \
    for (int kh = 0; kh < 2; ++kh) {                                                  \
        _Pragma("unroll")                                                             \
        for (int fm = 0; fm < 4; ++fm) {                                              \
            int r_ = wm * 128 + ((mh_) * 4 + fm) * 16 + (lane & 15);                  \
            u32 o_ = (u32)(r_ * 128 + kh * 64 + (lane >> 4) * 16);                    \
            o_ ^= (u32)((r_ & 7) << 4);                                               \
            SET_[kh][fm] = *(const s16x8*)((BUF_) + o_);                              \
        }                                                                             \
    }

#define RD_B(BUF_, nh_, SET_)                                                         \
    _Pragma("unroll")                                                                 \
    for (int kh = 0; kh < 2; ++kh) {                                                  \
        _Pragma("unroll")                                                             \
        for (int fn = 0; fn < 2; ++fn) {                                              \
            int c_ = wn * 64 + ((nh_) * 2 + fn) * 16 + (lane & 15);                   \
            u32 o_ = (u32)(c_ * 128 + kh * 64 + (lane >> 4) * 16);                    \
            o_ ^= (u32)((c_ & 7) << 4);                                               \
            SET_[kh][fn] = *(const s16x8*)((BUF_) + 32768 + o_);                      \
        }                                                                             \
    }

#define MM(AS_, BS_, mh_, nh_)                                                        \
    _Pragma("unroll")                                                                 \
    for (int kh = 0; kh < 2; ++kh) {                                                  \
        _Pragma("unroll")                                                             \
        for (int fm = 0; fm < 4; ++fm) {                                              \
            _Pragma("unroll")                                                         \
            for (int fn = 0; fn < 2; ++fn) {                                          \
                acc[(mh_) * 4 + fm][(nh_) * 2 + fn] =                                 \
                    __builtin_amdgcn_mfma_f32_16x16x32_bf16(                          \
                        AS_[kh][fm], BS_[kh][fn],                                     \
                        acc[(mh_) * 4 + fm][(nh_) * 2 + fn], 0, 0, 0);                \
            }                                                                         \
        }                                                                             \
    }

    // ---- prologue: stage tile 0 -> buf 0 ----
    STAGE_TILE(0, lds[0]);
    asm volatile("s_waitcnt vmcnt(0)" ::: "memory");
    __builtin_amdgcn_s_barrier();

    #pragma unroll 1
    for (int t = 0; t < 12; ++t) {
        const char* Bf = lds[t & 1];
        char* Of = lds[(t + 1) & 1];

        if (t < 11) STAGE_TILE(t + 1, Of);

        RD_A(Bf, 0, fA0);
        RD_B(Bf, 0, fB0);
        __builtin_amdgcn_s_setprio(1);
        MM(fA0, fB0, 0, 0);
        RD_B(Bf, 1, fB1);
        MM(fA0, fB1, 0, 1);
        RD_A(Bf, 1, fA1);
        MM(fA1, fB1, 1, 1);
        MM(fA1, fB0, 1, 0);
        __builtin_amdgcn_s_setprio(0);

        asm volatile("s_waitcnt vmcnt(0)" ::: "memory");
        __builtin_amdgcn_s_barrier();
    }

#undef STAGE_TILE
#undef RD_A
#undef RD_B
#undef MM

    // ---- residual staging: 4 j==i Ximg tiles (kk=0..3) -> 128KB LDS via
    // coalesced DMA (final loop barrier retired all LDS readers). ----
    {
        char* R = (char*)lds;
        #pragma unroll
        for (int kk = 0; kk < 4; ++kk) {
            const char* rs = XimgB + (((size_t)((ct * 256 + rtile) * 4 + kk)) << 15) + goff;
            #pragma unroll
            for (int q = 0; q < 4; ++q)
                gl2lds16(rs + q * 8192, R + kk * 32768 + q * 8192 + loff);
        }
        asm volatile("s_waitcnt vmcnt(0)" ::: "memory");
        __builtin_amdgcn_s_barrier();
    }

    // ---- epilogue: out = acc + bf16(x[i]) + bsum, residual from LDS ----
    const int r0 = (lane >> 4) * 4;
    const int cl = lane & 15;
    const char* Rb = (const char*)lds + (size_t)wn * 32768;
    #pragma unroll
    for (int mf = 0; mf < 8; ++mf) {
        #pragma unroll
        for (int nf = 0; nf < 4; ++nf) {
            int col_l = wn * 64 + nf * 16 + cl;
            float bs = bsum[col0 + col_l];
            #pragma unroll
            for (int r = 0; r < 4; ++r) {
                int row = wm * 128 + mf * 16 + r0 + r;
                int r2e = (nf * 16 + cl) ^ ((row & 7) << 3);
                float res = bf2f(*(const unsigned short*)(Rb + row * 128 + r2e * 2));
                int n = n0 + row;
                size_t oidx = ((size_t)ct * NN + n) * DD + col_l;
                out[oidx] = acc[mf][nf][r] + res + bs;
            }
        }
    }
}

// ---- Fallback (R2-verified kernel) for small ws_size ----
__global__ __launch_bounds__(256, 2) void fusion_gemm_fb(
    const float* __restrict__ x, const unsigned short* __restrict__ Wimg,
    const float* __restrict__ bsum, float* __restrict__ out) {
    __shared__ __attribute__((aligned(16))) unsigned short Alds[128 * 64];
    __shared__ __attribute__((aligned(16))) unsigned short Blds[2][128 * 64];

    const int tid = threadIdx.x;
    const int bid = blockIdx.x;
    const int xcd = bid & 7;
    const int slot = bid >> 3;
    const int ct = slot & 7;
    const int rhi = slot >> 3;
    const int rtile = rhi * 8 + xcd;
    const int n0 = rtile * 128;
    const int col0 = ct * 128;
    const int i = ct >> 1;

    const int lane = tid & 63;
    const int wid = tid >> 6;
    const int wm = wid >> 1;
    const int wn = wid & 1;

    f32x4 acc[4][4];
    #pragma unroll
    for (int a = 0; a < 4; ++a)
        #pragma unroll
        for (int b2 = 0; b2 < 4; ++b2)
            acc[a][b2] = (f32x4){0.f, 0.f, 0.f, 0.f};

    const int sr = tid >> 1;
    const int sh = tid & 1;
    char* Ab = (char*)Alds;
    const char* WimgB = (const char*)Wimg;

    f32x4 av[8];
    {
        int j0 = (i == 0) ? 1 : 0;
        const float* asrc = x + (size_t)j0 * ((size_t)NN * DD) + (size_t)(n0 + sr) * DD + sh * 32;
        #pragma unroll
        for (int q = 0; q < 8; ++q) av[q] = *(const f32x4*)(asrc + q * 4);
        const char* base = WimgB + (((size_t)(ct * 4 + j0) * 4 + 0) << 14) + wid * 1024 + lane * 16;
        char* lb = (char*)Blds[0] + wid * 1024;
        #pragma unroll
        for (int q = 0; q < 4; ++q) gl2lds16(base + q * 4096, lb + q * 4096);
    }

    for (int t = 0; t < 12; ++t) {
        __syncthreads();
        #pragma unroll
        for (int q = 0; q < 4; ++q) {
            f32x4 v0 = av[2 * q], v1 = av[2 * q + 1];
            u32x4 pk;
            pk[0] = (u32)f2bf(v0[0]) | ((u32)f2bf(v0[1]) << 16);
            pk[1] = (u32)f2bf(v0[2]) | ((u32)f2bf(v0[3]) << 16);
            pk[2] = (u32)f2bf(v1[0]) | ((u32)f2bf(v1[1]) << 16);
            pk[3] = (u32)f2bf(v1[2]) | ((u32)f2bf(v1[3]) << 16);
            u32 o = (u32)(sr * 128 + sh * 64 + q * 16);
            o ^= (u32)((sr & 7) << 4);
            *(u32x4*)(Ab + o) = pk;
        }
        __syncthreads();

        if (t < 11) {
            int tn = t + 1;
            int jjn = tn >> 2;
            int jn = jjn + (jjn >= i);
            int kkn = tn & 3;
            const char* base = WimgB + (((size_t)(ct * 4 + jn) * 4 + kkn) << 14) + wid * 1024 + lane * 16;
            char* lb = (char*)Blds[tn & 1] + wid * 1024;
            #pragma unroll
            for (int q = 0; q < 4; ++q) gl2lds16(base + q * 4096, lb + q * 4096);
            const float* asrc = x + (size_t)jn * ((size_t)NN * DD) + (size_t)(n0 + sr) * DD + kkn * 64 + sh * 32;
            #pragma unroll
            for (int q = 0; q < 8; ++q) av[q] = *(const f32x4*)(asrc + q * 4);
        }

        const char* Bb = (const char*)Blds[t & 1];
        #pragma unroll
        for (int kh = 0; kh < 2; ++kh) {
            s16x8 af[4], bfr[4];
            #pragma unroll
            for (int fm = 0; fm < 4; ++fm) {
                int row = wm * 64 + fm * 16 + (lane & 15);
                u32 o = (u32)(row * 128 + kh * 64 + (lane >> 4) * 16);
                o ^= (u32)((row & 7) << 4);
                af[fm] = *(const s16x8*)(Ab + o);
            }
            #pragma unroll
            for (int fn = 0; fn < 4; ++fn) {
                int col = wn * 64 + fn * 16 + (lane & 15);
                u32 o = (u32)(col * 128 + kh * 64 + (lane >> 4) * 16);
                o ^= (u32)((col & 7) << 4);
                bfr[fn] = *(const s16x8*)(Bb + o);
            }
            #pragma unroll
            for (int fm = 0; fm < 4; ++fm)
                #pragma unroll
                for (int fn = 0; fn < 4; ++fn)
                    acc[fm][fn] = __builtin_amdgcn_mfma_f32_16x16x32_bf16(
                        af[fm], bfr[fn], acc[fm][fn], 0, 0, 0);
        }
    }

    const int r0 = (lane >> 4) * 4;
    const int cl = lane & 15;
    #pragma unroll
    for (int fm = 0; fm < 4; ++fm) {
        #pragma unroll
        for (int fn = 0; fn < 4; ++fn) {
            int col_l = wn * 64 + fn * 16 + cl;
            int cglob = col0 + col_l;
            float bs = bsum[cglob];
            int e = cglob & 255;
            #pragma unroll
            for (int r = 0; r < 4; ++r) {
                int row_l = wm * 64 + fm * 16 + r0 + r;
                int n = n0 + row_l;
                size_t oidx = ((size_t)i * NN + n) * DD + e;
                out[oidx] = acc[fm][fn][r] + x[oidx] + bs;
            }
        }
    }
}

extern "C" void kernel_launch(void* const* d_in, const int* in_sizes, int n_in,
                              void* d_out, int out_size, void* d_ws, size_t ws_size,
                              hipStream_t stream) {
    const float* x = (const float*)d_in[0];
    const float* W = (const float*)d_in[1];
    const float* b = (const float*)d_in[2];
    float* out = (float*)d_out;

    unsigned short* Wimg = (unsigned short*)d_ws;                      // 8 MB (256-col) / 2 MB (fb)
    float* bsum = (float*)((char*)d_ws + ((size_t)8 << 20));           // 4 KB
    const size_t ximg_off = (size_t)9 << 20;
    const size_t need = ximg_off + ((size_t)128 << 20);                // 137 MB

    if (ws_size >= need) {
        unsigned short* Ximg = (unsigned short*)((char*)d_ws + ximg_off);
        hipLaunchKernelGGL(prep_all, dim3(66564), dim3(256), 0, stream, x, W, b, Wimg, Ximg, bsum);
        hipLaunchKernelGGL(fusion_gemm14, dim3(1024), dim3(512), 0, stream, Wimg, Ximg, bsum, out);
    } else {
        float* bsum2 = (float*)((char*)d_ws + ((size_t)2 << 20));
        hipLaunchKernelGGL(prep_b, dim3(4), dim3(256), 0, stream, b, bsum2);
        hipLaunchKernelGGL(prep_w128, dim3(1024), dim3(256), 0, stream, W, Wimg);
        hipLaunchKernelGGL(fusion_gemm_fb, dim3(4096), dim3(256), 0, stream, x, Wimg, bsum2, out);
    }
}